// Round 1
// baseline (1962.658 us; speedup 1.0000x reference)
//
#include <hip/hip_runtime.h>

// Problem constants (fixed shapes from setup_inputs)
constexpr int Bb  = 4;
constexpr int Tt  = 4096;
constexpr int Dd  = 1024;
constexpr int Mm  = Bb * Tt;        // 16384 rows
constexpr int NCH = 64;             // scan chunks
constexpr int CL  = Tt / NCH;       // 64 steps per chunk

#define LOG_INIT_F (-1e38f)
#define EPS_F      (1e-8f)

__device__ __forceinline__ float lae(float a, float b) {
    // logaddexp(a,b) = max + log(1 + exp(min-max)); matches jnp within ~1e-7
    float mx = fmaxf(a, b);
    float mn = fminf(a, b);
    return mx + __logf(1.0f + __expf(mn - mx));
}

// ---------------------------------------------------------------------------
// GEMM: C[m,n] = sum_d A'[m,d] * W[n,d]   (W row-major [N][K] == B^T layout)
// FUSE: A'[m,d] = x[m,d]*mix[d] + x[m-1,d]*(1-mix[d]), zero row at t==0.
// 128x128 tile, BK=32, 256 threads, 8x8 micro-tile per thread.
// ---------------------------------------------------------------------------
template<bool FUSE>
__global__ __launch_bounds__(256, 2)
void gemm_bt(const float* __restrict__ A, const float* __restrict__ mix,
             const float* __restrict__ W, float* __restrict__ C,
             int M, int N, int K) {
    __shared__ __align__(16) float As[32][132];   // k-major, padded stride
    __shared__ __align__(16) float Bs[32][132];

    const int tid  = threadIdx.x;
    const int m0   = blockIdx.y * 128;
    const int n0   = blockIdx.x * 128;
    const int srow = tid >> 3;            // 0..31
    const int scol = (tid & 7) << 2;      // 0,4,...,28
    const int tm   = (tid >> 4) << 3;     // 0..120 step 8
    const int tn   = (tid & 15) << 3;     // 0..120 step 8

    float acc[8][8];
    #pragma unroll
    for (int i = 0; i < 8; ++i)
        #pragma unroll
        for (int j = 0; j < 8; ++j) acc[i][j] = 0.f;

    for (int k0 = 0; k0 < K; k0 += 32) {
        float4 mv;
        if constexpr (FUSE) mv = *(const float4*)&mix[k0 + scol];
        #pragma unroll
        for (int rr = 0; rr < 128; rr += 32) {
            // A tile
            int m = m0 + srow + rr;
            const float* src = &A[(size_t)m * K + k0 + scol];
            float4 xv = *(const float4*)src;
            float4 av = xv;
            if constexpr (FUSE) {
                float4 lx = make_float4(0.f, 0.f, 0.f, 0.f);
                if ((m & (Tt - 1)) != 0) lx = *(const float4*)(src - K);
                av.x = xv.x * mv.x + lx.x * (1.f - mv.x);
                av.y = xv.y * mv.y + lx.y * (1.f - mv.y);
                av.z = xv.z * mv.z + lx.z * (1.f - mv.z);
                av.w = xv.w * mv.w + lx.w * (1.f - mv.w);
            }
            As[scol + 0][srow + rr] = av.x;
            As[scol + 1][srow + rr] = av.y;
            As[scol + 2][srow + rr] = av.z;
            As[scol + 3][srow + rr] = av.w;
            // B tile (weights)
            int n = n0 + srow + rr;
            float4 wv = *(const float4*)&W[(size_t)n * K + k0 + scol];
            Bs[scol + 0][srow + rr] = wv.x;
            Bs[scol + 1][srow + rr] = wv.y;
            Bs[scol + 2][srow + rr] = wv.z;
            Bs[scol + 3][srow + rr] = wv.w;
        }
        __syncthreads();
        #pragma unroll 8
        for (int kk = 0; kk < 32; ++kk) {
            float4 a0 = *(const float4*)&As[kk][tm];
            float4 a1 = *(const float4*)&As[kk][tm + 4];
            float4 b0 = *(const float4*)&Bs[kk][tn];
            float4 b1 = *(const float4*)&Bs[kk][tn + 4];
            float a[8]  = {a0.x, a0.y, a0.z, a0.w, a1.x, a1.y, a1.z, a1.w};
            float bv[8] = {b0.x, b0.y, b0.z, b0.w, b1.x, b1.y, b1.z, b1.w};
            #pragma unroll
            for (int i = 0; i < 8; ++i)
                #pragma unroll
                for (int j = 0; j < 8; ++j)
                    acc[i][j] = fmaf(a[i], bv[j], acc[i][j]);
        }
        __syncthreads();
    }
    #pragma unroll
    for (int i = 0; i < 8; ++i) {
        size_t row = (size_t)(m0 + tm + i) * N + n0 + tn;
        *(float4*)&C[row]     = make_float4(acc[i][0], acc[i][1], acc[i][2], acc[i][3]);
        *(float4*)&C[row + 4] = make_float4(acc[i][4], acc[i][5], acc[i][6], acc[i][7]);
    }
}

// ---------------------------------------------------------------------------
// WKV scan, chunk-parallel. Pass 1: per-chunk local final states (init -1e38).
// ---------------------------------------------------------------------------
__global__ void wkv_pass1(const float* __restrict__ k, const float* __restrict__ v,
                          const float* __restrict__ td,
                          float* __restrict__ lfp, float* __restrict__ lfm,
                          float* __restrict__ lfb) {
    int d = blockIdx.x * blockDim.x + threadIdx.x;
    int c = blockIdx.y, b = blockIdx.z;
    float w = __expf(td[d]);
    float ap = LOG_INIT_F, am = LOG_INIT_F, bbv = LOG_INIT_F;
    size_t base = ((size_t)b * Tt + (size_t)c * CL) * Dd + d;
    float kt = k[base], vt = v[base];
    for (int i = 0; i < CL; ++i) {
        float kn = 0.f, vn = 0.f;
        if (i + 1 < CL) {   // prefetch next step (coalesced over d)
            size_t nx = base + (size_t)(i + 1) * Dd;
            kn = k[nx]; vn = v[nx];
        }
        float lvp = __logf(fmaxf(vt, 0.f) + EPS_F);
        float lvm = __logf(fmaxf(-vt, 0.f) + EPS_F);
        ap  = lae(ap  - w, kt + lvp);
        am  = lae(am  - w, kt + lvm);
        bbv = lae(bbv - w, kt);
        kt = kn; vt = vn;
    }
    size_t o = ((size_t)b * NCH + c) * Dd + d;
    lfp[o] = ap; lfm[o] = am; lfb[o] = bbv;
}

// Pass 2: sequential combine over chunks (decay over a chunk is exactly L*w).
__global__ void wkv_pass2(const float* __restrict__ lfp, const float* __restrict__ lfm,
                          const float* __restrict__ lfb, const float* __restrict__ td,
                          float* __restrict__ sp, float* __restrict__ sm,
                          float* __restrict__ sb) {
    int idx = blockIdx.x * blockDim.x + threadIdx.x;   // over B*D
    int b = idx >> 10;          // / Dd
    int d = idx & (Dd - 1);
    float w  = __expf(td[d]);
    float Lw = (float)CL * w;
    float ap = LOG_INIT_F, am = LOG_INIT_F, bbv = LOG_INIT_F;
    for (int c = 0; c < NCH; ++c) {
        size_t o = ((size_t)b * NCH + c) * Dd + d;
        sp[o] = ap; sm[o] = am; sb[o] = bbv;   // incoming state for chunk c
        ap  = lae(ap  - Lw, lfp[o]);
        am  = lae(am  - Lw, lfm[o]);
        bbv = lae(bbv - Lw, lfb[o]);
    }
}

// Pass 3: exact reference recurrence per chunk, seeded with incoming state;
// emits y = wkv * sigmoid(r). k/y may alias (no __restrict__ on them).
__global__ void wkv_pass3(const float* k, const float* __restrict__ v,
                          const float* __restrict__ r,
                          const float* __restrict__ td, const float* __restrict__ tf,
                          const float* __restrict__ sp, const float* __restrict__ sm,
                          const float* __restrict__ sb, float* y) {
    int d = blockIdx.x * blockDim.x + threadIdx.x;
    int c = blockIdx.y, b = blockIdx.z;
    float w = __expf(td[d]);
    float u = tf[d];
    size_t so = ((size_t)b * NCH + c) * Dd + d;
    float ap = sp[so], am = sm[so], bbv = sb[so];
    size_t base = ((size_t)b * Tt + (size_t)c * CL) * Dd + d;
    float kt = k[base], vt = v[base], rt = r[base];
    for (int i = 0; i < CL; ++i) {
        float kn = 0.f, vn = 0.f, rn = 0.f;
        if (i + 1 < CL) {   // prefetch BEFORE the (possibly aliasing) y store
            size_t nx = base + (size_t)(i + 1) * Dd;
            kn = k[nx]; vn = v[nx]; rn = r[nx];
        }
        float lvp = __logf(fmaxf(vt, 0.f) + EPS_F);
        float lvm = __logf(fmaxf(-vt, 0.f) + EPS_F);
        float uk  = u + kt;
        float lden = lae(uk, bbv);
        float wkv = __expf(lae(uk + lvp, ap) - lden)
                  - __expf(lae(uk + lvm, am) - lden);
        float sr = 1.f / (1.f + __expf(-rt));
        y[base + (size_t)i * Dd] = wkv * sr;
        ap  = lae(ap  - w, kt + lvp);
        am  = lae(am  - w, kt + lvm);
        bbv = lae(bbv - w, kt);
        kt = kn; vt = vn; rt = rn;
    }
}

// ---------------------------------------------------------------------------
extern "C" void kernel_launch(void* const* d_in, const int* in_sizes, int n_in,
                              void* d_out, int out_size, void* d_ws, size_t ws_size,
                              hipStream_t stream) {
    const float* x   = (const float*)d_in[0];
    const float* td  = (const float*)d_in[1];
    const float* tf  = (const float*)d_in[2];
    const float* mk  = (const float*)d_in[3];
    const float* mv  = (const float*)d_in[4];
    const float* mr  = (const float*)d_in[5];
    const float* Wk  = (const float*)d_in[6];
    const float* Wv  = (const float*)d_in[7];
    const float* Wr  = (const float*)d_in[8];
    const float* Wo  = (const float*)d_in[9];
    float* out = (float*)d_out;
    float* ws  = (float*)d_ws;

    const size_t SZ = (size_t)Mm * Dd;          // 16,777,216 floats (64 MB)
    const size_t SS = (size_t)Bb * NCH * Dd;    // 262,144 floats per state array
    float* kb  = ws;
    float* vb  = ws + SZ;
    float* rb  = ws + 2 * SZ;
    float* st  = ws + 3 * SZ;
    float* lfp = st;
    float* lfm = st + SS;
    float* lfb = st + 2 * SS;
    float* sp  = st + 3 * SS;
    float* sm  = st + 4 * SS;
    float* sb  = st + 5 * SS;
    // y: separate buffer if workspace allows, else alias onto k (safe: pass3
    // reads k[i] / prefetches k[i+1] before writing y[i], same thread only).
    float* yb = kb;
    const size_t need_sep = (4 * SZ + 6 * SS) * sizeof(float);
    if (ws_size >= need_sep) yb = st + 6 * SS;

    dim3 gg(Dd / 128, Mm / 128);               // (8, 128) blocks
    gemm_bt<true ><<<gg, 256, 0, stream>>>(x, mk, Wk, kb, Mm, Dd, Dd);
    gemm_bt<true ><<<gg, 256, 0, stream>>>(x, mv, Wv, vb, Mm, Dd, Dd);
    gemm_bt<true ><<<gg, 256, 0, stream>>>(x, mr, Wr, rb, Mm, Dd, Dd);

    dim3 gs(Dd / 256, NCH, Bb);                // (4, 64, 4) blocks of 256
    wkv_pass1<<<gs, 256, 0, stream>>>(kb, vb, td, lfp, lfm, lfb);
    wkv_pass2<<<(Bb * Dd) / 256, 256, 0, stream>>>(lfp, lfm, lfb, td, sp, sm, sb);
    wkv_pass3<<<gs, 256, 0, stream>>>(kb, vb, rb, td, tf, sp, sm, sb, yb);

    gemm_bt<false><<<gg, 256, 0, stream>>>(yb, nullptr, Wo, out, Mm, Dd, Dd);
}

// Round 5
// 997.345 us; speedup vs baseline: 1.9679x; 1.9679x over previous
//
#include <hip/hip_runtime.h>
#include <stdint.h>

typedef unsigned short u16;
typedef __bf16 bf16x8 __attribute__((ext_vector_type(8)));
typedef float  f32x16 __attribute__((ext_vector_type(16)));
typedef int    i32x4  __attribute__((ext_vector_type(4)));

constexpr int Bb  = 4;
constexpr int Tt  = 4096;
constexpr int Dd  = 1024;
constexpr int Mm  = Bb * Tt;        // 16384 rows
constexpr int NCH = 64;             // scan chunks
constexpr int CL  = Tt / NCH;       // 64 steps per chunk

#define LOG_INIT_F (-1e38f)
#define EPS_F      (1e-8f)

__device__ __forceinline__ float lae(float a, float b) {
    float mx = fmaxf(a, b);
    float mn = fminf(a, b);
    return mx + __logf(1.0f + __expf(mn - mx));
}

// bf16 round-to-nearest-even split helpers
__device__ __forceinline__ u16 f2bf(float f) {
    unsigned u = __float_as_uint(f);
    return (u16)((u + 0x7fffu + ((u >> 16) & 1u)) >> 16);
}
__device__ __forceinline__ float bf2f(u16 h) {
    return __uint_as_float(((unsigned)h) << 16);
}

// async global->LDS, 16B per lane. LDS dest must be wave-uniform base;
// global src is per-lane (pre-swizzled into MFMA fragment order).
// Direct generic->as(3) addrspacecast (canonical clang form).
__device__ __forceinline__ void async_cp16(const u16* g, u16* l) {
    __builtin_amdgcn_global_load_lds(
        (const __attribute__((address_space(1))) unsigned int*)g,
        (__attribute__((address_space(3))) unsigned int*)l,
        16, 0, 0);
}

__device__ __forceinline__ f32x16 mfma32(i32x4 a, i32x4 b, f32x16 c) {
    return __builtin_amdgcn_mfma_f32_32x32x16_bf16(
        __builtin_bit_cast(bf16x8, a), __builtin_bit_cast(bf16x8, b), c, 0, 0, 0);
}

// ---------------------------------------------------------------------------
// bf16x3 split GEMM: C[m,n] = sum_k (Ah+Al)[m,k]*(Bh+Bl)[n,k]  (~fp32 accurate)
// A arrays [M][K] bf16, B arrays [N][K] bf16 (= B^T layout), C fp32 [M][N].
// 128x128 tile, BK=32, 4 waves; wave w stages matrix w via global_load_lds
// into fragment-ordered LDS (frag = 32x16 bf16 slice, lane-linear 16B).
// mfma_f32_32x32x16_bf16: A row=l&31,k=(l>>5)*8+j ; B col=l&31, same k;
// C/D col=lane&31, row=(r&3)+8*(r>>2)+4*(lane>>5)  [m74/m101-verified].
// ---------------------------------------------------------------------------
__global__ __launch_bounds__(256, 2)
void gemm3(const u16* __restrict__ Ah, const u16* __restrict__ Al,
           const u16* __restrict__ Bh, const u16* __restrict__ Bl,
           float* __restrict__ C, int M, int N, int K) {
    __shared__ __align__(16) u16 smem[4 * 4096];   // Ah|Al|Bh|Bl, 8KB each
    u16* const sAh = smem;
    u16* const sAl = smem + 4096;
    u16* const sBh = smem + 8192;
    u16* const sBl = smem + 12288;

    const int tid  = threadIdx.x;
    const int lane = tid & 63;
    const int w    = tid >> 6;         // 0..3
    const int wr   = w >> 1, wc = w & 1;
    const int m0   = blockIdx.y * 128;
    const int n0   = blockIdx.x * 128;

    const u16* gsrc; u16* sdst; int row0;
    switch (w) {
        case 0:  gsrc = Ah; sdst = sAh; row0 = m0; break;
        case 1:  gsrc = Al; sdst = sAl; row0 = m0; break;
        case 2:  gsrc = Bh; sdst = sBh; row0 = n0; break;
        default: gsrc = Bl; sdst = sBl; row0 = n0; break;
    }
    // per-lane fragment-swizzled global base: row = row0 + (lane&31), k-octet by lane>>5
    const u16* g0 = gsrc + (size_t)(row0 + (lane & 31)) * K + ((lane >> 5) * 8);

    f32x16 acc[2][2] = {};

    for (int k0 = 0; k0 < K; k0 += 32) {
        // stage: 8 frags (kh in {0,1} x rowblock rb in {0..3}), 1KB each
        #pragma unroll
        for (int f = 0; f < 8; ++f) {
            const int kh = f >> 2, rb = f & 3;
            async_cp16(g0 + (size_t)rb * 32 * K + (k0 + kh * 16), sdst + f * 512);
        }
        __syncthreads();   // compiler drains vmcnt before s_barrier -> staged data visible

        i32x4 ah[2][2], al[2][2], bh[2][2], bl[2][2];   // [kh][sub-block]
        #pragma unroll
        for (int kh = 0; kh < 2; ++kh)
            #pragma unroll
            for (int i = 0; i < 2; ++i) {
                ah[kh][i] = *(const i32x4*)&sAh[(kh * 4 + wr * 2 + i) * 512 + lane * 8];
                al[kh][i] = *(const i32x4*)&sAl[(kh * 4 + wr * 2 + i) * 512 + lane * 8];
                bh[kh][i] = *(const i32x4*)&sBh[(kh * 4 + wc * 2 + i) * 512 + lane * 8];
                bl[kh][i] = *(const i32x4*)&sBl[(kh * 4 + wc * 2 + i) * 512 + lane * 8];
            }
        #pragma unroll
        for (int kh = 0; kh < 2; ++kh)
            #pragma unroll
            for (int i = 0; i < 2; ++i)
                #pragma unroll
                for (int j = 0; j < 2; ++j) {
                    acc[i][j] = mfma32(ah[kh][i], bh[kh][j], acc[i][j]);
                    acc[i][j] = mfma32(ah[kh][i], bl[kh][j], acc[i][j]);
                    acc[i][j] = mfma32(al[kh][i], bh[kh][j], acc[i][j]);
                }
        __syncthreads();   // all reads done before next stage overwrites
    }

    const int colb = n0 + wc * 64 + (lane & 31);
    #pragma unroll
    for (int i = 0; i < 2; ++i)
        #pragma unroll
        for (int j = 0; j < 2; ++j)
            #pragma unroll
            for (int r = 0; r < 16; ++r) {
                int row = m0 + wr * 64 + i * 32 + (r & 3) + 8 * (r >> 2) + 4 * (lane >> 5);
                C[(size_t)row * N + colb + j * 32] = acc[i][j][r];
            }
}

// ---------------------------------------------------------------------------
// Split a weight matrix (row-major [N][K] fp32) into bf16 hi/lo arrays.
// ---------------------------------------------------------------------------
__global__ void splitw(const float* __restrict__ W, u16* __restrict__ h,
                       u16* __restrict__ l) {
    size_t i = (size_t)(blockIdx.x * 256 + threadIdx.x) * 4;
    float4 v = *(const float4*)&W[i];
    u16 h0 = f2bf(v.x), h1 = f2bf(v.y), h2 = f2bf(v.z), h3 = f2bf(v.w);
    ushort4 hv = { h0, h1, h2, h3 };
    ushort4 lv = { f2bf(v.x - bf2f(h0)), f2bf(v.y - bf2f(h1)),
                   f2bf(v.z - bf2f(h2)), f2bf(v.w - bf2f(h3)) };
    *(ushort4*)&h[i] = hv;
    *(ushort4*)&l[i] = lv;
}

// Fused time-mix + hi/lo split of x:  a = x*mix + lastx*(1-mix), lastx=0 at t==0.
__global__ void mixsplit(const float* __restrict__ x, const float* __restrict__ mix,
                         u16* __restrict__ xh, u16* __restrict__ xl) {
    int idx = blockIdx.x * 256 + threadIdx.x;   // quad index over M*D/4
    int d4  = idx & (Dd / 4 - 1);
    int m   = idx >> 8;
    size_t e = (size_t)m * Dd + d4 * 4;
    float4 xv = *(const float4*)&x[e];
    float4 mv = *(const float4*)&mix[d4 * 4];
    float4 lx = make_float4(0.f, 0.f, 0.f, 0.f);
    if ((m & (Tt - 1)) != 0) lx = *(const float4*)&x[e - Dd];
    float a0 = xv.x * mv.x + lx.x * (1.f - mv.x);
    float a1 = xv.y * mv.y + lx.y * (1.f - mv.y);
    float a2 = xv.z * mv.z + lx.z * (1.f - mv.z);
    float a3 = xv.w * mv.w + lx.w * (1.f - mv.w);
    u16 h0 = f2bf(a0), h1 = f2bf(a1), h2 = f2bf(a2), h3 = f2bf(a3);
    ushort4 hv = { h0, h1, h2, h3 };
    ushort4 lv = { f2bf(a0 - bf2f(h0)), f2bf(a1 - bf2f(h1)),
                   f2bf(a2 - bf2f(h2)), f2bf(a3 - bf2f(h3)) };
    *(ushort4*)&xh[e] = hv;
    *(ushort4*)&xl[e] = lv;
}

// ---------------------------------------------------------------------------
// WKV scan, chunk-parallel (unchanged numerics from the passing round).
// ---------------------------------------------------------------------------
__global__ void wkv_pass1(const float* __restrict__ k, const float* __restrict__ v,
                          const float* __restrict__ td,
                          float* __restrict__ lfp, float* __restrict__ lfm,
                          float* __restrict__ lfb) {
    int d = blockIdx.x * blockDim.x + threadIdx.x;
    int c = blockIdx.y, b = blockIdx.z;
    float w = __expf(td[d]);
    float ap = LOG_INIT_F, am = LOG_INIT_F, bbv = LOG_INIT_F;
    size_t base = ((size_t)b * Tt + (size_t)c * CL) * Dd + d;
    float kt = k[base], vt = v[base];
    for (int i = 0; i < CL; ++i) {
        float kn = 0.f, vn = 0.f;
        if (i + 1 < CL) {
            size_t nx = base + (size_t)(i + 1) * Dd;
            kn = k[nx]; vn = v[nx];
        }
        float lvp = __logf(fmaxf(vt, 0.f) + EPS_F);
        float lvm = __logf(fmaxf(-vt, 0.f) + EPS_F);
        ap  = lae(ap  - w, kt + lvp);
        am  = lae(am  - w, kt + lvm);
        bbv = lae(bbv - w, kt);
        kt = kn; vt = vn;
    }
    size_t o = ((size_t)b * NCH + c) * Dd + d;
    lfp[o] = ap; lfm[o] = am; lfb[o] = bbv;
}

__global__ void wkv_pass2(const float* __restrict__ lfp, const float* __restrict__ lfm,
                          const float* __restrict__ lfb, const float* __restrict__ td,
                          float* __restrict__ sp, float* __restrict__ sm,
                          float* __restrict__ sb) {
    int idx = blockIdx.x * blockDim.x + threadIdx.x;   // over B*D
    int b = idx >> 10;
    int d = idx & (Dd - 1);
    float w  = __expf(td[d]);
    float Lw = (float)CL * w;
    float ap = LOG_INIT_F, am = LOG_INIT_F, bbv = LOG_INIT_F;
    for (int c = 0; c < NCH; ++c) {
        size_t o = ((size_t)b * NCH + c) * Dd + d;
        sp[o] = ap; sm[o] = am; sb[o] = bbv;
        ap  = lae(ap  - Lw, lfp[o]);
        am  = lae(am  - Lw, lfm[o]);
        bbv = lae(bbv - Lw, lfb[o]);
    }
}

// Pass 3: exact recurrence per chunk; emits y = wkv*sigmoid(r) split to bf16 hi/lo.
__global__ void wkv_pass3(const float* __restrict__ k, const float* __restrict__ v,
                          const float* __restrict__ r,
                          const float* __restrict__ td, const float* __restrict__ tf,
                          const float* __restrict__ sp, const float* __restrict__ sm,
                          const float* __restrict__ sb,
                          u16* __restrict__ yh, u16* __restrict__ yl) {
    int d = blockIdx.x * blockDim.x + threadIdx.x;
    int c = blockIdx.y, b = blockIdx.z;
    float w = __expf(td[d]);
    float u = tf[d];
    size_t so = ((size_t)b * NCH + c) * Dd + d;
    float ap = sp[so], am = sm[so], bbv = sb[so];
    size_t base = ((size_t)b * Tt + (size_t)c * CL) * Dd + d;
    float kt = k[base], vt = v[base], rt = r[base];
    for (int i = 0; i < CL; ++i) {
        float kn = 0.f, vn = 0.f, rn = 0.f;
        if (i + 1 < CL) {
            size_t nx = base + (size_t)(i + 1) * Dd;
            kn = k[nx]; vn = v[nx]; rn = r[nx];
        }
        float lvp = __logf(fmaxf(vt, 0.f) + EPS_F);
        float lvm = __logf(fmaxf(-vt, 0.f) + EPS_F);
        float uk  = u + kt;
        float lden = lae(uk, bbv);
        float wkv = __expf(lae(uk + lvp, ap) - lden)
                  - __expf(lae(uk + lvm, am) - lden);
        float sr = 1.f / (1.f + __expf(-rt));
        float yv = wkv * sr;
        size_t pos = base + (size_t)i * Dd;
        u16 h = f2bf(yv);
        yh[pos] = h;
        yl[pos] = f2bf(yv - bf2f(h));
        ap  = lae(ap  - w, kt + lvp);
        am  = lae(am  - w, kt + lvm);
        bbv = lae(bbv - w, kt);
        kt = kn; vt = vn; rt = rn;
    }
}

// ---------------------------------------------------------------------------
// Workspace (fits the proven 207.6 MB extent = 3*SZ + 6*SS floats):
//   [0,SZ)   kb fp32      [SZ,2SZ) vb fp32
//   [2SZ,3SZ) xh+xl bf16  (mixed-x splits, later reused for y splits)
//   [3SZ, +6SS) region R: W hi/lo splits (4MB, per-GEMM) time-shared with
//                          scan states (6MB, lf* then s*)
//   r lives in d_out until pass3 consumes it.
// ---------------------------------------------------------------------------
extern "C" void kernel_launch(void* const* d_in, const int* in_sizes, int n_in,
                              void* d_out, int out_size, void* d_ws, size_t ws_size,
                              hipStream_t stream) {
    const float* x   = (const float*)d_in[0];
    const float* td  = (const float*)d_in[1];
    const float* tf  = (const float*)d_in[2];
    const float* mk  = (const float*)d_in[3];
    const float* mv  = (const float*)d_in[4];
    const float* mr  = (const float*)d_in[5];
    const float* Wk  = (const float*)d_in[6];
    const float* Wv  = (const float*)d_in[7];
    const float* Wr  = (const float*)d_in[8];
    const float* Wo  = (const float*)d_in[9];
    float* out = (float*)d_out;
    float* ws  = (float*)d_ws;

    const size_t SZ = (size_t)Mm * Dd;          // 16,777,216
    const size_t SS = (size_t)Bb * NCH * Dd;    // 262,144

    float* kb = ws;
    float* vb = ws + SZ;
    u16*   xh = (u16*)(ws + 2 * SZ);
    u16*   xl = xh + SZ;
    float* R  = ws + 3 * SZ;
    u16*   Wh = (u16*)R;
    u16*   Wl = Wh + (size_t)Dd * Dd;
    float* lfp = R;            float* lfm = R + SS;      float* lfb = R + 2 * SS;
    float* sp  = R + 3 * SS;   float* sm  = R + 4 * SS;  float* sb  = R + 5 * SS;
    float* rb  = out;          // r parked in d_out until pass3

    dim3 gw((Dd * Dd) / (256 * 4));             // 1024 blocks
    dim3 gx((Mm * Dd) / (256 * 4));             // 16384 blocks
    dim3 gg(Dd / 128, Mm / 128);                // (8,128)
    dim3 gs(Dd / 256, NCH, Bb);                 // (4,64,4)

    splitw<<<gw, 256, 0, stream>>>(Wk, Wh, Wl);
    mixsplit<<<gx, 256, 0, stream>>>(x, mk, xh, xl);
    gemm3<<<gg, 256, 0, stream>>>(xh, xl, Wh, Wl, kb, Mm, Dd, Dd);

    splitw<<<gw, 256, 0, stream>>>(Wv, Wh, Wl);
    mixsplit<<<gx, 256, 0, stream>>>(x, mv, xh, xl);
    gemm3<<<gg, 256, 0, stream>>>(xh, xl, Wh, Wl, vb, Mm, Dd, Dd);

    splitw<<<gw, 256, 0, stream>>>(Wr, Wh, Wl);
    mixsplit<<<gx, 256, 0, stream>>>(x, mr, xh, xl);
    gemm3<<<gg, 256, 0, stream>>>(xh, xl, Wh, Wl, rb, Mm, Dd, Dd);

    wkv_pass1<<<gs, 256, 0, stream>>>(kb, vb, td, lfp, lfm, lfb);
    wkv_pass2<<<(Bb * Dd) / 256, 256, 0, stream>>>(lfp, lfm, lfb, td, sp, sm, sb);
    wkv_pass3<<<gs, 256, 0, stream>>>(kb, vb, rb, td, tf, sp, sm, sb, xh, xl);

    splitw<<<gw, 256, 0, stream>>>(Wo, Wh, Wl);   // states dead; reuse R
    gemm3<<<gg, 256, 0, stream>>>(xh, xl, Wh, Wl, out, Mm, Dd, Dd);
}